// Round 8
// baseline (1154.726 us; speedup 1.0000x reference)
//
#include <hip/hip_runtime.h>
#include <hip/hip_fp16.h>

#define N_NODES    100000
#define N_EDGES    3200000
#define HIDDEN     64
#define NUM_GRAPHS 128
#define NUM_LABELS 1000

#define BKT_SHIFT  7
#define NPB        128                              // nodes per bucket
#define NBKT       ((N_NODES + NPB - 1) / NPB)      // 782
#define CHUNK      2048
#define NBLK_E     ((N_EDGES + CHUNK - 1) / CHUNK)  // 1563
#define ENTCAP     5632                             // LDS staging capacity (45 KB)

// ---------------- zero int fill ----------------
__global__ void zero_int_kernel(int* __restrict__ p, int n) {
    int i = blockIdx.x * blockDim.x + threadIdx.x;
    if (i < n) p[i] = 0;
}

// ---------------- degree via global atomics (L2-resident 400 KB) ----------------
__global__ void deg_kernel(const int* __restrict__ dst, const float* __restrict__ ew,
                           float* __restrict__ deg, int E) {
    int i = blockIdx.x * blockDim.x + threadIdx.x;
    if (i < E) atomicAdd(&deg[dst[i]], ew[i]);
}

__global__ void dinv_kernel(const float* __restrict__ deg, float* __restrict__ dinv, int n) {
    int i = blockIdx.x * blockDim.x + threadIdx.x;
    if (i < n) dinv[i] = rsqrtf(deg[i] + 1.0f);
}

// ---------------- K1: bucket histogram ----------------
__global__ __launch_bounds__(256) void hist_kernel(const int* __restrict__ dst,
                                                   int* __restrict__ bcnt, int E) {
    __shared__ int h[NBKT];
    int t = threadIdx.x;
    for (int b = t; b < NBKT; b += 256) h[b] = 0;
    __syncthreads();
    int base = blockIdx.x * CHUNK;
    int end  = min(base + CHUNK, E);
    for (int i = base + t; i < end; i += 256)
        atomicAdd(&h[dst[i] >> BKT_SHIFT], 1);
    __syncthreads();
    for (int b = t; b < NBKT; b += 256) {
        int c = h[b];
        if (c) atomicAdd(&bcnt[b], c);
    }
}

// ---------------- K2: scan bucket counts -> offsets + cursors; also zero gsum ----------------
__global__ __launch_bounds__(1024) void scan_buckets_kernel(const int* __restrict__ bcnt,
                                                            int* __restrict__ boff,
                                                            int* __restrict__ bktCur,
                                                            float* __restrict__ gsum) {
    __shared__ int a[1024], b[1024];
    int t = threadIdx.x;
    for (int k = t; k < NUM_GRAPHS * 64; k += 1024) gsum[k] = 0.f;
    int v = (t < NBKT) ? bcnt[t] : 0;
    a[t] = v; __syncthreads();
    int* pa = a; int* pb = b;
    #pragma unroll
    for (int d = 1; d < 1024; d <<= 1) {
        int x = pa[t];
        if (t >= d) x += pa[t - d];
        pb[t] = x; __syncthreads();
        int* tmp = pa; pa = pb; pb = tmp;
    }
    int ex = (t == 0) ? 0 : pa[t - 1];
    if (t < NBKT) { boff[t] = ex; bktCur[t] = ex; }
    if (t == NBKT - 1) boff[NBKT] = pa[t];
}

// ---------------- K3: scatter edges into bucket-contiguous buffer ----------------
// barr entry: x = src | (dstoff << 20), y = bits(ew)
__global__ __launch_bounds__(256) void bucket_scatter_kernel(
    const int* __restrict__ src, const int* __restrict__ dst,
    const float* __restrict__ ew, int* __restrict__ bktCur,
    int2* __restrict__ barr, int E) {
    __shared__ int h[NBKT];
    __shared__ int wbase[NBKT];
    int t = threadIdx.x;
    for (int b = t; b < NBKT; b += 256) h[b] = 0;
    __syncthreads();
    int base = blockIdx.x * CHUNK;
    int end  = min(base + CHUNK, E);
    for (int i = base + t; i < end; i += 256)
        atomicAdd(&h[dst[i] >> BKT_SHIFT], 1);
    __syncthreads();
    for (int b = t; b < NBKT; b += 256) {
        int c = h[b];
        wbase[b] = c ? atomicAdd(&bktCur[b], c) : 0;
    }
    __syncthreads();
    for (int b = t; b < NBKT; b += 256) h[b] = 0;
    __syncthreads();
    for (int i = base + t; i < end; i += 256) {
        int d = dst[i];
        int bk = d >> BKT_SHIFT;
        int p = atomicAdd(&h[bk], 1);
        barr[wbase[bk] + p] = make_int2(src[i] | ((d & (NPB - 1)) << 20),
                                        __float_as_int(ew[i]));
    }
}

// ---------------- K4: combined per-bucket finalize -> off + CSR ----------------
// csr entry: x = src | (labels[src] << 17), y = bits(ew * dinv[dst] * dinv[src])
__global__ __launch_bounds__(256) void finalize_kernel(
    const int2* __restrict__ barr, const int* __restrict__ boff,
    const float* __restrict__ dinv, const int* __restrict__ labels,
    int2* __restrict__ csr, int* __restrict__ off) {
    __shared__ int2  ent[ENTCAP];
    __shared__ int   hcnt[NPB];
    __shared__ int   ha[NPB], hcur[NPB];
    __shared__ float ldv[NPB];
    int b = blockIdx.x;
    int t = threadIdx.x;
    int s = boff[b], e = boff[b + 1];
    int m = e - s;
    int node0 = b << BKT_SHIFT;
    int nn = min(NPB, N_NODES - node0);
    if (t < NPB) {
        hcnt[t] = 0;
        ldv[t]  = (t < nn) ? dinv[node0 + t] : 0.f;
    }
    __syncthreads();
    bool staged = (m <= ENTCAP);
    for (int i = t; i < m; i += 256) {
        int2 v = barr[s + i];
        if (staged) ent[i] = v;
        atomicAdd(&hcnt[(v.x >> 20) & (NPB - 1)], 1);
    }
    __syncthreads();
    if (t < NPB) ha[t] = hcnt[t];
    __syncthreads();
    #pragma unroll
    for (int d = 1; d < NPB; d <<= 1) {
        int x = 0;
        if (t < NPB) { x = ha[t]; if (t >= d) x += ha[t - d]; }
        __syncthreads();
        if (t < NPB) ha[t] = x;
        __syncthreads();
    }
    if (t < NPB) {
        int ex = (t == 0) ? 0 : ha[t - 1];
        hcur[t] = s + ex;
        if (t < nn) off[node0 + t] = s + ex;
    }
    if (b == NBKT - 1 && t == 0) off[N_NODES] = e;
    __syncthreads();
    for (int i = t; i < m; i += 256) {
        int2 v = staged ? ent[i] : barr[s + i];
        int doff = (v.x >> 20) & (NPB - 1);
        int sv   = v.x & 0xFFFFF;                 // src (17 bits used)
        float wf = __int_as_float(v.y) * ldv[doff] * dinv[sv];
        int lab  = labels[sv];
        int p = atomicAdd(&hcur[doff], 1);
        csr[p] = make_int2(sv | (lab << 17), __float_as_int(wf));
    }
}

// ---------------- EW1 = emb @ W1 (1000x64), fp16 out, no bias/relu ----------------
__global__ __launch_bounds__(256) void ew1_kernel(
    const float* __restrict__ emb, const float* __restrict__ W,
    __half* __restrict__ OUTH) {
    __shared__ float Ws[64 * 64];
    __shared__ float Xs[64 * 65];
    int t = threadIdx.x;
    #pragma unroll
    for (int s = 0; s < 16; ++s) Ws[s * 256 + t] = W[s * 256 + t];
    int r0   = blockIdx.x * 64;
    int lrow = t >> 2;
    int c0   = (t & 3) * 16;
    int grow = r0 + lrow;
    const float* srcrow = (grow < NUM_LABELS) ? (emb + (size_t)grow * HIDDEN) : emb;
    #pragma unroll
    for (int c = 0; c < 16; c += 4) {
        float4 v = *(const float4*)(srcrow + c0 + c);
        Xs[lrow * 65 + c0 + c + 0] = v.x;
        Xs[lrow * 65 + c0 + c + 1] = v.y;
        Xs[lrow * 65 + c0 + c + 2] = v.z;
        Xs[lrow * 65 + c0 + c + 3] = v.w;
    }
    __syncthreads();
    int row = t & 63;
    int j0  = (t >> 6) * 16;
    float4 a0 = make_float4(0,0,0,0), a1 = a0, a2 = a0, a3 = a0;
    #pragma unroll
    for (int k = 0; k < 64; ++k) {
        float xv = Xs[row * 65 + k];
        const float4* wr = (const float4*)(Ws + k * 64 + j0);
        float4 w0 = wr[0], w1 = wr[1], w2 = wr[2], w3 = wr[3];
        a0.x = fmaf(xv, w0.x, a0.x); a0.y = fmaf(xv, w0.y, a0.y);
        a0.z = fmaf(xv, w0.z, a0.z); a0.w = fmaf(xv, w0.w, a0.w);
        a1.x = fmaf(xv, w1.x, a1.x); a1.y = fmaf(xv, w1.y, a1.y);
        a1.z = fmaf(xv, w1.z, a1.z); a1.w = fmaf(xv, w1.w, a1.w);
        a2.x = fmaf(xv, w2.x, a2.x); a2.y = fmaf(xv, w2.y, a2.y);
        a2.z = fmaf(xv, w2.z, a2.z); a2.w = fmaf(xv, w2.w, a2.w);
        a3.x = fmaf(xv, w3.x, a3.x); a3.y = fmaf(xv, w3.y, a3.y);
        a3.z = fmaf(xv, w3.z, a3.z); a3.w = fmaf(xv, w3.w, a3.w);
    }
    int gr = r0 + row;
    if (gr < NUM_LABELS) {
        union { __half2 h2[8]; uint4 u4[2]; } pk;
        pk.h2[0] = __floats2half2_rn(a0.x, a0.y);
        pk.h2[1] = __floats2half2_rn(a0.z, a0.w);
        pk.h2[2] = __floats2half2_rn(a1.x, a1.y);
        pk.h2[3] = __floats2half2_rn(a1.z, a1.w);
        pk.h2[4] = __floats2half2_rn(a2.x, a2.y);
        pk.h2[5] = __floats2half2_rn(a2.z, a2.w);
        pk.h2[6] = __floats2half2_rn(a3.x, a3.y);
        pk.h2[7] = __floats2half2_rn(a3.z, a3.w);
        uint4* o = (uint4*)(OUTH + (size_t)gr * HIDDEN + j0);
        o[0] = pk.u4[0]; o[1] = pk.u4[1];
    }
}

// ---------------- conv1: agg over EW1[label] rows -> A1 = relu(acc + di2*self + b1), fp16 out ----------------
__global__ __launch_bounds__(256) void agg1_kernel(
    const __half* __restrict__ EW1h, const int* __restrict__ labels,
    const int2* __restrict__ csr, const int* __restrict__ off,
    const float* __restrict__ dinv, const float* __restrict__ bias,
    __half* __restrict__ A1h, int n) {
    int wid  = (blockIdx.x * blockDim.x + threadIdx.x) >> 6;
    if (wid >= n) return;
    int lane = threadIdx.x & 63;
    int q = lane & 15, g = lane >> 4;
    int i   = off[wid] + g;
    int end = off[wid + 1];
    float4 acc = make_float4(0.f, 0.f, 0.f, 0.f);
    int2 e0 = (i     < end) ? csr[i]     : make_int2(0, 0);
    int2 e1 = (i + 4 < end) ? csr[i + 4] : make_int2(0, 0);
    uint2  r0 = *(const uint2*)(EW1h + (size_t)((unsigned)e0.x >> 17) * HIDDEN + q * 4);
    float  w0 = __int_as_float(e0.y);
    while (i < end) {
        int2 e2 = (i + 8 < end) ? csr[i + 8] : make_int2(0, 0);
        uint2  r1 = *(const uint2*)(EW1h + (size_t)((unsigned)e1.x >> 17) * HIDDEN + q * 4);
        float  w1 = __int_as_float(e1.y);
        const __half2* hp = (const __half2*)&r0;
        float2 f01 = __half22float2(hp[0]);
        float2 f23 = __half22float2(hp[1]);
        acc.x = fmaf(f01.x, w0, acc.x);
        acc.y = fmaf(f01.y, w0, acc.y);
        acc.z = fmaf(f23.x, w0, acc.z);
        acc.w = fmaf(f23.y, w0, acc.w);
        w0 = w1; r0 = r1; e1 = e2;
        i += 4;
    }
    acc.x += __shfl_xor(acc.x, 16, 64); acc.y += __shfl_xor(acc.y, 16, 64);
    acc.z += __shfl_xor(acc.z, 16, 64); acc.w += __shfl_xor(acc.w, 16, 64);
    acc.x += __shfl_xor(acc.x, 32, 64); acc.y += __shfl_xor(acc.y, 32, 64);
    acc.z += __shfl_xor(acc.z, 32, 64); acc.w += __shfl_xor(acc.w, 32, 64);
    if (g == 0) {
        float di  = dinv[wid];
        float di2 = di * di;
        int labw = labels[wid];
        uint2 xu = *(const uint2*)(EW1h + (size_t)labw * HIDDEN + q * 4);
        const __half2* xp = (const __half2*)&xu;
        float2 x01 = __half22float2(xp[0]);
        float2 x23 = __half22float2(xp[1]);
        float4 bv = *(const float4*)(bias + q * 4);
        float4 v;
        v.x = fmaxf(fmaf(x01.x, di2, acc.x) + bv.x, 0.f);
        v.y = fmaxf(fmaf(x01.y, di2, acc.y) + bv.y, 0.f);
        v.z = fmaxf(fmaf(x23.x, di2, acc.z) + bv.z, 0.f);
        v.w = fmaxf(fmaf(x23.y, di2, acc.w) + bv.w, 0.f);
        union { __half2 h2[2]; uint2 u2; } pk;
        pk.h2[0] = __floats2half2_rn(v.x, v.y);
        pk.h2[1] = __floats2half2_rn(v.z, v.w);
        *(uint2*)(A1h + (size_t)wid * HIDDEN + q * 4) = pk.u2;
    }
}

// ---------------- conv2 pull aggregation (fp16 activation gather) -> fp32 out ----------------
__global__ __launch_bounds__(256) void agg2_kernel(
    const __half* __restrict__ Xh,
    const int2* __restrict__ csr, const int* __restrict__ off,
    const float* __restrict__ dinv, float* __restrict__ OUT, int n) {
    int wid  = (blockIdx.x * blockDim.x + threadIdx.x) >> 6;
    if (wid >= n) return;
    int lane = threadIdx.x & 63;
    int q = lane & 15, g = lane >> 4;
    int i   = off[wid] + g;
    int end = off[wid + 1];
    float4 acc = make_float4(0.f, 0.f, 0.f, 0.f);
    int2 e0 = (i     < end) ? csr[i]     : make_int2(0, 0);
    int2 e1 = (i + 4 < end) ? csr[i + 4] : make_int2(0, 0);
    uint2  r0 = *(const uint2*)(Xh + (size_t)(e0.x & 0x1FFFF) * HIDDEN + q * 4);
    float  w0 = __int_as_float(e0.y);
    while (i < end) {
        int2 e2 = (i + 8 < end) ? csr[i + 8] : make_int2(0, 0);
        uint2  r1 = *(const uint2*)(Xh + (size_t)(e1.x & 0x1FFFF) * HIDDEN + q * 4);
        float  w1 = __int_as_float(e1.y);
        const __half2* hp = (const __half2*)&r0;
        float2 f01 = __half22float2(hp[0]);
        float2 f23 = __half22float2(hp[1]);
        acc.x = fmaf(f01.x, w0, acc.x);
        acc.y = fmaf(f01.y, w0, acc.y);
        acc.z = fmaf(f23.x, w0, acc.z);
        acc.w = fmaf(f23.y, w0, acc.w);
        w0 = w1; r0 = r1; e1 = e2;
        i += 4;
    }
    acc.x += __shfl_xor(acc.x, 16, 64); acc.y += __shfl_xor(acc.y, 16, 64);
    acc.z += __shfl_xor(acc.z, 16, 64); acc.w += __shfl_xor(acc.w, 16, 64);
    acc.x += __shfl_xor(acc.x, 32, 64); acc.y += __shfl_xor(acc.y, 32, 64);
    acc.z += __shfl_xor(acc.z, 32, 64); acc.w += __shfl_xor(acc.w, 32, 64);
    if (g == 0) {
        float di  = dinv[wid];
        float di2 = di * di;
        uint2 xu = *(const uint2*)(Xh + (size_t)wid * HIDDEN + q * 4);
        const __half2* xp = (const __half2*)&xu;
        float2 x01 = __half22float2(xp[0]);
        float2 x23 = __half22float2(xp[1]);
        float4 v;
        v.x = fmaf(x01.x, di2, acc.x);
        v.y = fmaf(x01.y, di2, acc.y);
        v.z = fmaf(x23.x, di2, acc.z);
        v.w = fmaf(x23.y, di2, acc.w);
        *(float4*)(OUT + (size_t)wid * HIDDEN + q * 4) = v;
    }
}

// ---------------- GEMM + bias + relu + fused mean-pool accumulation ----------------
__global__ __launch_bounds__(256) void gemm_pool_kernel(
    const float* __restrict__ X, const float* __restrict__ W,
    const float* __restrict__ bias,
    const int* __restrict__ batch, float* __restrict__ gsum, int n) {
    __shared__ float Ws[64 * 64];
    __shared__ float Xs[64 * 65];
    int t = threadIdx.x;
    #pragma unroll
    for (int s = 0; s < 16; ++s) Ws[s * 256 + t] = W[s * 256 + t];
    int r0   = blockIdx.x * 64;
    int lrow = t >> 2;
    int c0   = (t & 3) * 16;
    int grow = r0 + lrow;
    const float* srcrow = (grow < n) ? (X + (size_t)grow * HIDDEN) : X;
    #pragma unroll
    for (int c = 0; c < 16; c += 4) {
        float4 v = *(const float4*)(srcrow + c0 + c);
        Xs[lrow * 65 + c0 + c + 0] = v.x;
        Xs[lrow * 65 + c0 + c + 1] = v.y;
        Xs[lrow * 65 + c0 + c + 2] = v.z;
        Xs[lrow * 65 + c0 + c + 3] = v.w;
    }
    __syncthreads();
    int row = t & 63;
    int j0  = (t >> 6) * 16;
    float4 a0 = *(const float4*)(bias + j0 + 0);
    float4 a1 = *(const float4*)(bias + j0 + 4);
    float4 a2 = *(const float4*)(bias + j0 + 8);
    float4 a3 = *(const float4*)(bias + j0 + 12);
    #pragma unroll
    for (int k = 0; k < 64; ++k) {
        float xv = Xs[row * 65 + k];
        const float4* wr = (const float4*)(Ws + k * 64 + j0);
        float4 w0 = wr[0], w1 = wr[1], w2 = wr[2], w3 = wr[3];
        a0.x = fmaf(xv, w0.x, a0.x); a0.y = fmaf(xv, w0.y, a0.y);
        a0.z = fmaf(xv, w0.z, a0.z); a0.w = fmaf(xv, w0.w, a0.w);
        a1.x = fmaf(xv, w1.x, a1.x); a1.y = fmaf(xv, w1.y, a1.y);
        a1.z = fmaf(xv, w1.z, a1.z); a1.w = fmaf(xv, w1.w, a1.w);
        a2.x = fmaf(xv, w2.x, a2.x); a2.y = fmaf(xv, w2.y, a2.y);
        a2.z = fmaf(xv, w2.z, a2.z); a2.w = fmaf(xv, w2.w, a2.w);
        a3.x = fmaf(xv, w3.x, a3.x); a3.y = fmaf(xv, w3.y, a3.y);
        a3.z = fmaf(xv, w3.z, a3.z); a3.w = fmaf(xv, w3.w, a3.w);
    }
    a0.x = fmaxf(a0.x, 0.f); a0.y = fmaxf(a0.y, 0.f); a0.z = fmaxf(a0.z, 0.f); a0.w = fmaxf(a0.w, 0.f);
    a1.x = fmaxf(a1.x, 0.f); a1.y = fmaxf(a1.y, 0.f); a1.z = fmaxf(a1.z, 0.f); a1.w = fmaxf(a1.w, 0.f);
    a2.x = fmaxf(a2.x, 0.f); a2.y = fmaxf(a2.y, 0.f); a2.z = fmaxf(a2.z, 0.f); a2.w = fmaxf(a2.w, 0.f);
    a3.x = fmaxf(a3.x, 0.f); a3.y = fmaxf(a3.y, 0.f); a3.z = fmaxf(a3.z, 0.f); a3.w = fmaxf(a3.w, 0.f);
    int gr = r0 + row;
    bool valid = (gr < n);
    int brow  = valid ? batch[gr] : 0x7fffffff;
    int bmaxv = valid ? brow      : -1;
    int gmin = brow, gmax = bmaxv;
    #pragma unroll
    for (int o = 1; o < 64; o <<= 1) {
        gmin = min(gmin, __shfl_xor(gmin, o, 64));
        gmax = max(gmax, __shfl_xor(gmax, o, 64));
    }
    const float4 z = make_float4(0.f, 0.f, 0.f, 0.f);
    for (int gg = gmin; gg <= gmax; ++gg) {
        bool m = (brow == gg);
        float4 v0 = m ? a0 : z, v1 = m ? a1 : z, v2 = m ? a2 : z, v3 = m ? a3 : z;
        #pragma unroll
        for (int o = 1; o < 64; o <<= 1) {
            v0.x += __shfl_xor(v0.x, o, 64); v0.y += __shfl_xor(v0.y, o, 64);
            v0.z += __shfl_xor(v0.z, o, 64); v0.w += __shfl_xor(v0.w, o, 64);
            v1.x += __shfl_xor(v1.x, o, 64); v1.y += __shfl_xor(v1.y, o, 64);
            v1.z += __shfl_xor(v1.z, o, 64); v1.w += __shfl_xor(v1.w, o, 64);
            v2.x += __shfl_xor(v2.x, o, 64); v2.y += __shfl_xor(v2.y, o, 64);
            v2.z += __shfl_xor(v2.z, o, 64); v2.w += __shfl_xor(v2.w, o, 64);
            v3.x += __shfl_xor(v3.x, o, 64); v3.y += __shfl_xor(v3.y, o, 64);
            v3.z += __shfl_xor(v3.z, o, 64); v3.w += __shfl_xor(v3.w, o, 64);
        }
        if (row == 0) {
            float* gp = gsum + (size_t)gg * HIDDEN + j0;
            atomicAdd(gp + 0,  v0.x); atomicAdd(gp + 1,  v0.y);
            atomicAdd(gp + 2,  v0.z); atomicAdd(gp + 3,  v0.w);
            atomicAdd(gp + 4,  v1.x); atomicAdd(gp + 5,  v1.y);
            atomicAdd(gp + 6,  v1.z); atomicAdd(gp + 7,  v1.w);
            atomicAdd(gp + 8,  v2.x); atomicAdd(gp + 9,  v2.y);
            atomicAdd(gp + 10, v2.z); atomicAdd(gp + 11, v2.w);
            atomicAdd(gp + 12, v3.x); atomicAdd(gp + 13, v3.y);
            atomicAdd(gp + 14, v3.z); atomicAdd(gp + 15, v3.w);
        }
    }
}

// ---------------- head: mean -> relu(g@W3+b3) -> @W4+b4 ----------------
__global__ __launch_bounds__(64) void head_kernel(
    const float* __restrict__ gsum, const int* __restrict__ batch,
    const float* __restrict__ W3, const float* __restrict__ b3,
    const float* __restrict__ W4, const float* __restrict__ b4,
    float* __restrict__ out) {
    __shared__ int   sb[2];
    __shared__ float gv[64];
    int gidx = blockIdx.x;
    int t = threadIdx.x;
    if (t < 2) {
        int target = gidx + t;
        int lo = 0, hi = N_NODES;
        while (lo < hi) {
            int mid = (lo + hi) >> 1;
            if (batch[mid] < target) lo = mid + 1; else hi = mid;
        }
        sb[t] = lo;
    }
    __syncthreads();
    float cnt = (float)(sb[1] - sb[0]);
    gv[t] = gsum[gidx * 64 + t] / fmaxf(cnt, 1.0f);
    __syncthreads();
    float acc = b3[t];
    #pragma unroll
    for (int k = 0; k < 64; ++k) acc = fmaf(gv[k], W3[k * 64 + t], acc);
    float p = fmaxf(acc, 0.f) * W4[t];
    #pragma unroll
    for (int o = 32; o > 0; o >>= 1) p += __shfl_down(p, o, 64);
    if (t == 0) out[gidx] = p + b4[0];
}

extern "C" void kernel_launch(void* const* d_in, const int* in_sizes, int n_in,
                              void* d_out, int out_size, void* d_ws, size_t ws_size,
                              hipStream_t stream) {
    const int*   labels = (const int*)d_in[0];
    const int*   ei     = (const int*)d_in[1];
    const int*   src    = ei;
    const int*   dst    = ei + N_EDGES;
    const float* ew     = (const float*)d_in[2];
    const int*   batch  = (const int*)d_in[3];
    const float* emb    = (const float*)d_in[4];
    const float* W1 = (const float*)d_in[5],  *b1 = (const float*)d_in[6];
    const float* W2 = (const float*)d_in[7],  *b2 = (const float*)d_in[8];
    const float* W3 = (const float*)d_in[9],  *b3 = (const float*)d_in[10];
    const float* W4 = (const float*)d_in[11], *b4 = (const float*)d_in[12];
    float* out = (float*)d_out;

    // workspace carve
    float* ws   = (float*)d_ws;
    float* bufH = ws;                                       // N*64 fp32 (agg2 out / gemm2 in)
    float* bufA = bufH + (size_t)N_NODES * HIDDEN;          // N*64 fp32 region: barr, then A1h (fp16)
    int2*  csr  = (int2*)(bufA + (size_t)N_NODES * HIDDEN); // E int2
    float* deg    = (float*)(csr + N_EDGES);                // N
    int*   bcnt   = (int*)(deg + N_NODES);                  // NBKT (contiguous w/ deg for zeroing)
    int*   boff   = bcnt + NBKT;                            // NBKT+1
    int*   bktCur = boff + NBKT + 1;                        // NBKT
    int*   off    = bktCur + NBKT;                          // N+1
    float* dinv   = (float*)(off + N_NODES + 1);            // N
    float* gsum   = dinv + N_NODES;                         // 128*64
    __half* EW1h  = (__half*)(gsum + NUM_GRAPHS * 64);      // 1000*64 fp16
    int2*  barr   = (int2*)bufA;                            // aliases bufA (dead after finalize)
    __half* A1h   = (__half*)bufA;                          // fp16 activation, after finalize

    const int NT = 256;
    const int blkW = (N_NODES * 64 + NT - 1) / NT;          // wave per node
    const int blkG = (N_NODES + 63) / 64;
    const int blkE = (N_EDGES + NT - 1) / NT;
    const int blkN = (N_NODES + NT - 1) / NT;

    // ---- degree + dinv (global atomics, L2-resident counters) ----
    zero_int_kernel<<<(N_NODES + NBKT + NT - 1) / NT, NT, 0, stream>>>((int*)deg, N_NODES + NBKT);
    deg_kernel<<<blkE, NT, 0, stream>>>(dst, ew, deg, N_EDGES);
    dinv_kernel<<<blkN, NT, 0, stream>>>(deg, dinv, N_NODES);

    // ---- CSR build ----
    hist_kernel<<<NBLK_E, NT, 0, stream>>>(dst, bcnt, N_EDGES);
    scan_buckets_kernel<<<1, 1024, 0, stream>>>(bcnt, boff, bktCur, gsum);
    bucket_scatter_kernel<<<NBLK_E, NT, 0, stream>>>(src, dst, ew, bktCur, barr, N_EDGES);
    finalize_kernel<<<NBKT, NT, 0, stream>>>(barr, boff, dinv, labels, csr, off);

    // ---- conv1: EW1 = emb@W1 (fp16), then direct agg -> A1h ----
    ew1_kernel<<<(NUM_LABELS + 63) / 64, NT, 0, stream>>>(emb, W1, EW1h);
    agg1_kernel<<<blkW, NT, 0, stream>>>(EW1h, labels, csr, off, dinv, b1, A1h, N_NODES);

    // ---- conv2: aggregate A1h, GEMM fused with mean-pool ----
    agg2_kernel<<<blkW, NT, 0, stream>>>(A1h, csr, off, dinv, bufH, N_NODES);
    gemm_pool_kernel<<<blkG, NT, 0, stream>>>(bufH, W2, b2, batch, gsum, N_NODES);

    // ---- head ----
    head_kernel<<<NUM_GRAPHS, 64, 0, stream>>>(gsum, batch, W3, b3, W4, b4, out);
}

// Round 9
// 546.032 us; speedup vs baseline: 2.1148x; 2.1148x over previous
//
#include <hip/hip_runtime.h>
#include <hip/hip_fp16.h>

#define N_NODES    100000
#define N_EDGES    3200000
#define HIDDEN     64
#define NUM_GRAPHS 128
#define NUM_LABELS 1000

#define BKT_SHIFT  7
#define NPB        128                              // nodes per bucket
#define NBKT       ((N_NODES + NPB - 1) / NPB)      // 782
#define CHUNK      2048
#define NBLK_E     ((N_EDGES + CHUNK - 1) / CHUNK)  // 1563
#define ENTCAP     5632                             // LDS staging capacity (45 KB)

// ---------------- zero int fill ----------------
__global__ void zero_int_kernel(int* __restrict__ p, int n) {
    int i = blockIdx.x * blockDim.x + threadIdx.x;
    if (i < n) p[i] = 0;
}

// ---------------- K1: bucket histogram ----------------
__global__ __launch_bounds__(256) void hist_kernel(const int* __restrict__ dst,
                                                   int* __restrict__ bcnt, int E) {
    __shared__ int h[NBKT];
    int t = threadIdx.x;
    for (int b = t; b < NBKT; b += 256) h[b] = 0;
    __syncthreads();
    int base = blockIdx.x * CHUNK;
    int end  = min(base + CHUNK, E);
    for (int i = base + t; i < end; i += 256)
        atomicAdd(&h[dst[i] >> BKT_SHIFT], 1);
    __syncthreads();
    for (int b = t; b < NBKT; b += 256) {
        int c = h[b];
        if (c) atomicAdd(&bcnt[b], c);
    }
}

// ---------------- K2: scan bucket counts -> offsets + cursors ----------------
__global__ __launch_bounds__(1024) void scan_buckets_kernel(const int* __restrict__ bcnt,
                                                            int* __restrict__ boff,
                                                            int* __restrict__ bktCur) {
    __shared__ int a[1024], b[1024];
    int t = threadIdx.x;
    int v = (t < NBKT) ? bcnt[t] : 0;
    a[t] = v; __syncthreads();
    int* pa = a; int* pb = b;
    #pragma unroll
    for (int d = 1; d < 1024; d <<= 1) {
        int x = pa[t];
        if (t >= d) x += pa[t - d];
        pb[t] = x; __syncthreads();
        int* tmp = pa; pa = pb; pb = tmp;
    }
    int ex = (t == 0) ? 0 : pa[t - 1];
    if (t < NBKT) { boff[t] = ex; bktCur[t] = ex; }
    if (t == NBKT - 1) boff[NBKT] = pa[t];
}

// ---------------- K3: scatter edges into bucket-contiguous buffer ----------------
// barr entry: x = src | (dstoff << 20), y = bits(ew)
__global__ __launch_bounds__(256) void bucket_scatter_kernel(
    const int* __restrict__ src, const int* __restrict__ dst,
    const float* __restrict__ ew, int* __restrict__ bktCur,
    int2* __restrict__ barr, int E) {
    __shared__ int h[NBKT];
    __shared__ int wbase[NBKT];
    int t = threadIdx.x;
    for (int b = t; b < NBKT; b += 256) h[b] = 0;
    __syncthreads();
    int base = blockIdx.x * CHUNK;
    int end  = min(base + CHUNK, E);
    for (int i = base + t; i < end; i += 256)
        atomicAdd(&h[dst[i] >> BKT_SHIFT], 1);
    __syncthreads();
    for (int b = t; b < NBKT; b += 256) {
        int c = h[b];
        wbase[b] = c ? atomicAdd(&bktCur[b], c) : 0;
    }
    __syncthreads();
    for (int b = t; b < NBKT; b += 256) h[b] = 0;
    __syncthreads();
    for (int i = base + t; i < end; i += 256) {
        int d = dst[i];
        int bk = d >> BKT_SHIFT;
        int p = atomicAdd(&h[bk], 1);
        barr[wbase[bk] + p] = make_int2(src[i] | ((d & (NPB - 1)) << 20),
                                        __float_as_int(ew[i]));
    }
}

// ---------------- K4: merged per-bucket finalize -> off + dinv + CSR ----------------
// csr entry: x = src | (labels[src] << 17), y = bits(ew * dinv[dst])
__global__ __launch_bounds__(256) void finalize_kernel(
    const int2* __restrict__ barr, const int* __restrict__ boff,
    const int* __restrict__ labels,
    int2* __restrict__ csr, int* __restrict__ off, float* __restrict__ dinv) {
    __shared__ int2  ent[ENTCAP];
    __shared__ int   hcnt[NPB];
    __shared__ float wsum[NPB];
    __shared__ float ldv[NPB];
    __shared__ int   ha[NPB], hcur[NPB];
    int b = blockIdx.x;
    int t = threadIdx.x;
    int s = boff[b], e = boff[b + 1];
    int m = e - s;
    int node0 = b << BKT_SHIFT;
    int nn = min(NPB, N_NODES - node0);
    if (t < NPB) { hcnt[t] = 0; wsum[t] = 0.f; }
    __syncthreads();
    bool staged = (m <= ENTCAP);
    for (int i = t; i < m; i += 256) {
        int2 v = barr[s + i];
        if (staged) ent[i] = v;
        int doff = (v.x >> 20) & (NPB - 1);
        atomicAdd(&hcnt[doff], 1);
        atomicAdd(&wsum[doff], __int_as_float(v.y));
    }
    __syncthreads();
    if (t < NPB) ha[t] = hcnt[t];
    __syncthreads();
    #pragma unroll
    for (int d = 1; d < NPB; d <<= 1) {
        int x = 0;
        if (t < NPB) { x = ha[t]; if (t >= d) x += ha[t - d]; }
        __syncthreads();
        if (t < NPB) ha[t] = x;
        __syncthreads();
    }
    if (t < NPB) {
        int ex = (t == 0) ? 0 : ha[t - 1];
        hcur[t] = s + ex;
        float dv = rsqrtf(wsum[t] + 1.0f);
        ldv[t] = dv;
        if (t < nn) {
            off[node0 + t]  = s + ex;
            dinv[node0 + t] = dv;
        }
    }
    if (b == NBKT - 1 && t == 0) off[N_NODES] = e;
    __syncthreads();
    for (int i = t; i < m; i += 256) {
        int2 v = staged ? ent[i] : barr[s + i];
        int doff = (v.x >> 20) & (NPB - 1);
        int sv   = v.x & 0xFFFFF;                 // src (17 bits used)
        float wf = __int_as_float(v.y) * ldv[doff];    // dinv[dst] folded
        int lab  = labels[sv];
        int p = atomicAdd(&hcur[doff], 1);
        csr[p] = make_int2(sv | (lab << 17), __float_as_int(wf));
    }
}

// ---------------- EW1 = emb @ W1 (1000x64), fp16 out ----------------
__global__ __launch_bounds__(256) void ew1_kernel(
    const float* __restrict__ emb, const float* __restrict__ W,
    __half* __restrict__ OUTH) {
    __shared__ float Ws[64 * 64];
    __shared__ float Xs[64 * 65];
    int t = threadIdx.x;
    #pragma unroll
    for (int s = 0; s < 16; ++s) Ws[s * 256 + t] = W[s * 256 + t];
    int r0   = blockIdx.x * 64;
    int lrow = t >> 2;
    int c0   = (t & 3) * 16;
    int grow = r0 + lrow;
    const float* srcrow = (grow < NUM_LABELS) ? (emb + (size_t)grow * HIDDEN) : emb;
    #pragma unroll
    for (int c = 0; c < 16; c += 4) {
        float4 v = *(const float4*)(srcrow + c0 + c);
        Xs[lrow * 65 + c0 + c + 0] = v.x;
        Xs[lrow * 65 + c0 + c + 1] = v.y;
        Xs[lrow * 65 + c0 + c + 2] = v.z;
        Xs[lrow * 65 + c0 + c + 3] = v.w;
    }
    __syncthreads();
    int row = t & 63;
    int j0  = (t >> 6) * 16;
    float4 a0 = make_float4(0,0,0,0), a1 = a0, a2 = a0, a3 = a0;
    #pragma unroll
    for (int k = 0; k < 64; ++k) {
        float xv = Xs[row * 65 + k];
        const float4* wr = (const float4*)(Ws + k * 64 + j0);
        float4 w0 = wr[0], w1 = wr[1], w2 = wr[2], w3 = wr[3];
        a0.x = fmaf(xv, w0.x, a0.x); a0.y = fmaf(xv, w0.y, a0.y);
        a0.z = fmaf(xv, w0.z, a0.z); a0.w = fmaf(xv, w0.w, a0.w);
        a1.x = fmaf(xv, w1.x, a1.x); a1.y = fmaf(xv, w1.y, a1.y);
        a1.z = fmaf(xv, w1.z, a1.z); a1.w = fmaf(xv, w1.w, a1.w);
        a2.x = fmaf(xv, w2.x, a2.x); a2.y = fmaf(xv, w2.y, a2.y);
        a2.z = fmaf(xv, w2.z, a2.z); a2.w = fmaf(xv, w2.w, a2.w);
        a3.x = fmaf(xv, w3.x, a3.x); a3.y = fmaf(xv, w3.y, a3.y);
        a3.z = fmaf(xv, w3.z, a3.z); a3.w = fmaf(xv, w3.w, a3.w);
    }
    int gr = r0 + row;
    if (gr < NUM_LABELS) {
        union { __half2 h2[8]; uint4 u4[2]; } pk;
        pk.h2[0] = __floats2half2_rn(a0.x, a0.y);
        pk.h2[1] = __floats2half2_rn(a0.z, a0.w);
        pk.h2[2] = __floats2half2_rn(a1.x, a1.y);
        pk.h2[3] = __floats2half2_rn(a1.z, a1.w);
        pk.h2[4] = __floats2half2_rn(a2.x, a2.y);
        pk.h2[5] = __floats2half2_rn(a2.z, a2.w);
        pk.h2[6] = __floats2half2_rn(a3.x, a3.y);
        pk.h2[7] = __floats2half2_rn(a3.z, a3.w);
        uint4* o = (uint4*)(OUTH + (size_t)gr * HIDDEN + j0);
        o[0] = pk.u4[0]; o[1] = pk.u4[1];
    }
}

// ---------------- conv1: agg over EW1[label] -> A1 = relu(acc + di2*self + b1), fp16 out ----------------
__global__ __launch_bounds__(256) void agg1_kernel(
    const __half* __restrict__ EW1h, const int* __restrict__ labels,
    const int2* __restrict__ csr, const int* __restrict__ off,
    const float* __restrict__ dinv, const float* __restrict__ bias,
    __half* __restrict__ A1h, int n) {
    int wid  = (blockIdx.x * blockDim.x + threadIdx.x) >> 6;
    if (wid >= n) return;
    int lane = threadIdx.x & 63;
    int q = lane & 15, g = lane >> 4;
    int i   = off[wid] + g;
    int end = off[wid + 1];
    float4 acc = make_float4(0.f, 0.f, 0.f, 0.f);
    int2 e0 = (i     < end) ? csr[i]     : make_int2(0, 0);
    int2 e1 = (i + 4 < end) ? csr[i + 4] : make_int2(0, 0);
    uint2  r0 = *(const uint2*)(EW1h + (size_t)((unsigned)e0.x >> 17) * HIDDEN + q * 4);
    float  w0 = __int_as_float(e0.y) * dinv[e0.x & 0x1FFFF];
    while (i < end) {
        int2 e2 = (i + 8 < end) ? csr[i + 8] : make_int2(0, 0);
        uint2  r1 = *(const uint2*)(EW1h + (size_t)((unsigned)e1.x >> 17) * HIDDEN + q * 4);
        float  w1 = __int_as_float(e1.y) * dinv[e1.x & 0x1FFFF];
        const __half2* hp = (const __half2*)&r0;
        float2 f01 = __half22float2(hp[0]);
        float2 f23 = __half22float2(hp[1]);
        acc.x = fmaf(f01.x, w0, acc.x);
        acc.y = fmaf(f01.y, w0, acc.y);
        acc.z = fmaf(f23.x, w0, acc.z);
        acc.w = fmaf(f23.y, w0, acc.w);
        w0 = w1; r0 = r1; e1 = e2;
        i += 4;
    }
    acc.x += __shfl_xor(acc.x, 16, 64); acc.y += __shfl_xor(acc.y, 16, 64);
    acc.z += __shfl_xor(acc.z, 16, 64); acc.w += __shfl_xor(acc.w, 16, 64);
    acc.x += __shfl_xor(acc.x, 32, 64); acc.y += __shfl_xor(acc.y, 32, 64);
    acc.z += __shfl_xor(acc.z, 32, 64); acc.w += __shfl_xor(acc.w, 32, 64);
    if (g == 0) {
        float di  = dinv[wid];
        float di2 = di * di;
        int labw = labels[wid];
        uint2 xu = *(const uint2*)(EW1h + (size_t)labw * HIDDEN + q * 4);
        const __half2* xp = (const __half2*)&xu;
        float2 x01 = __half22float2(xp[0]);
        float2 x23 = __half22float2(xp[1]);
        float4 bv = *(const float4*)(bias + q * 4);
        float4 v;
        v.x = fmaxf(fmaf(x01.x, di2, acc.x) + bv.x, 0.f);
        v.y = fmaxf(fmaf(x01.y, di2, acc.y) + bv.y, 0.f);
        v.z = fmaxf(fmaf(x23.x, di2, acc.z) + bv.z, 0.f);
        v.w = fmaxf(fmaf(x23.y, di2, acc.w) + bv.w, 0.f);
        union { __half2 h2[2]; uint2 u2; } pk;
        pk.h2[0] = __floats2half2_rn(v.x, v.y);
        pk.h2[1] = __floats2half2_rn(v.z, v.w);
        *(uint2*)(A1h + (size_t)wid * HIDDEN + q * 4) = pk.u2;
    }
}

// ---------------- conv2 pull aggregation (fp16 activation gather) -> fp32 out ----------------
__global__ __launch_bounds__(256) void agg2_kernel(
    const __half* __restrict__ Xh,
    const int2* __restrict__ csr, const int* __restrict__ off,
    const float* __restrict__ dinv, float* __restrict__ OUT, int n) {
    int wid  = (blockIdx.x * blockDim.x + threadIdx.x) >> 6;
    if (wid >= n) return;
    int lane = threadIdx.x & 63;
    int q = lane & 15, g = lane >> 4;
    int i   = off[wid] + g;
    int end = off[wid + 1];
    float4 acc = make_float4(0.f, 0.f, 0.f, 0.f);
    int2 e0 = (i     < end) ? csr[i]     : make_int2(0, 0);
    int2 e1 = (i + 4 < end) ? csr[i + 4] : make_int2(0, 0);
    uint2  r0 = *(const uint2*)(Xh + (size_t)(e0.x & 0x1FFFF) * HIDDEN + q * 4);
    float  w0 = __int_as_float(e0.y) * dinv[e0.x & 0x1FFFF];
    while (i < end) {
        int2 e2 = (i + 8 < end) ? csr[i + 8] : make_int2(0, 0);
        uint2  r1 = *(const uint2*)(Xh + (size_t)(e1.x & 0x1FFFF) * HIDDEN + q * 4);
        float  w1 = __int_as_float(e1.y) * dinv[e1.x & 0x1FFFF];
        const __half2* hp = (const __half2*)&r0;
        float2 f01 = __half22float2(hp[0]);
        float2 f23 = __half22float2(hp[1]);
        acc.x = fmaf(f01.x, w0, acc.x);
        acc.y = fmaf(f01.y, w0, acc.y);
        acc.z = fmaf(f23.x, w0, acc.z);
        acc.w = fmaf(f23.y, w0, acc.w);
        w0 = w1; r0 = r1; e1 = e2;
        i += 4;
    }
    acc.x += __shfl_xor(acc.x, 16, 64); acc.y += __shfl_xor(acc.y, 16, 64);
    acc.z += __shfl_xor(acc.z, 16, 64); acc.w += __shfl_xor(acc.w, 16, 64);
    acc.x += __shfl_xor(acc.x, 32, 64); acc.y += __shfl_xor(acc.y, 32, 64);
    acc.z += __shfl_xor(acc.z, 32, 64); acc.w += __shfl_xor(acc.w, 32, 64);
    if (g == 0) {
        float di  = dinv[wid];
        float di2 = di * di;
        uint2 xu = *(const uint2*)(Xh + (size_t)wid * HIDDEN + q * 4);
        const __half2* xp = (const __half2*)&xu;
        float2 x01 = __half22float2(xp[0]);
        float2 x23 = __half22float2(xp[1]);
        float4 v;
        v.x = fmaf(x01.x, di2, acc.x);
        v.y = fmaf(x01.y, di2, acc.y);
        v.z = fmaf(x23.x, di2, acc.z);
        v.w = fmaf(x23.y, di2, acc.w);
        *(float4*)(OUT + (size_t)wid * HIDDEN + q * 4) = v;
    }
}

// ---------------- GEMM + bias + relu -> fp32 out (no pooling; low VGPR) ----------------
__global__ __launch_bounds__(256) void gemm2_kernel(
    const float* __restrict__ X, const float* __restrict__ W,
    const float* __restrict__ bias, float* __restrict__ OUT, int n) {
    __shared__ float Ws[64 * 64];
    __shared__ float Xs[64 * 65];
    int t = threadIdx.x;
    #pragma unroll
    for (int s = 0; s < 16; ++s) Ws[s * 256 + t] = W[s * 256 + t];
    int r0   = blockIdx.x * 64;
    int lrow = t >> 2;
    int c0   = (t & 3) * 16;
    int grow = r0 + lrow;
    const float* srcrow = (grow < n) ? (X + (size_t)grow * HIDDEN) : X;
    #pragma unroll
    for (int c = 0; c < 16; c += 4) {
        float4 v = *(const float4*)(srcrow + c0 + c);
        Xs[lrow * 65 + c0 + c + 0] = v.x;
        Xs[lrow * 65 + c0 + c + 1] = v.y;
        Xs[lrow * 65 + c0 + c + 2] = v.z;
        Xs[lrow * 65 + c0 + c + 3] = v.w;
    }
    __syncthreads();
    int row = t & 63;
    int j0  = (t >> 6) * 16;
    float4 a0 = *(const float4*)(bias + j0 + 0);
    float4 a1 = *(const float4*)(bias + j0 + 4);
    float4 a2 = *(const float4*)(bias + j0 + 8);
    float4 a3 = *(const float4*)(bias + j0 + 12);
    #pragma unroll
    for (int k = 0; k < 64; ++k) {
        float xv = Xs[row * 65 + k];
        const float4* wr = (const float4*)(Ws + k * 64 + j0);
        float4 w0 = wr[0], w1 = wr[1], w2 = wr[2], w3 = wr[3];
        a0.x = fmaf(xv, w0.x, a0.x); a0.y = fmaf(xv, w0.y, a0.y);
        a0.z = fmaf(xv, w0.z, a0.z); a0.w = fmaf(xv, w0.w, a0.w);
        a1.x = fmaf(xv, w1.x, a1.x); a1.y = fmaf(xv, w1.y, a1.y);
        a1.z = fmaf(xv, w1.z, a1.z); a1.w = fmaf(xv, w1.w, a1.w);
        a2.x = fmaf(xv, w2.x, a2.x); a2.y = fmaf(xv, w2.y, a2.y);
        a2.z = fmaf(xv, w2.z, a2.z); a2.w = fmaf(xv, w2.w, a2.w);
        a3.x = fmaf(xv, w3.x, a3.x); a3.y = fmaf(xv, w3.y, a3.y);
        a3.z = fmaf(xv, w3.z, a3.z); a3.w = fmaf(xv, w3.w, a3.w);
    }
    int gr = r0 + row;
    if (gr < n) {
        float4* o = (float4*)(OUT + (size_t)gr * HIDDEN + j0);
        a0.x = fmaxf(a0.x, 0.f); a0.y = fmaxf(a0.y, 0.f); a0.z = fmaxf(a0.z, 0.f); a0.w = fmaxf(a0.w, 0.f);
        a1.x = fmaxf(a1.x, 0.f); a1.y = fmaxf(a1.y, 0.f); a1.z = fmaxf(a1.z, 0.f); a1.w = fmaxf(a1.w, 0.f);
        a2.x = fmaxf(a2.x, 0.f); a2.y = fmaxf(a2.y, 0.f); a2.z = fmaxf(a2.z, 0.f); a2.w = fmaxf(a2.w, 0.f);
        a3.x = fmaxf(a3.x, 0.f); a3.y = fmaxf(a3.y, 0.f); a3.z = fmaxf(a3.z, 0.f); a3.w = fmaxf(a3.w, 0.f);
        o[0] = a0; o[1] = a1; o[2] = a2; o[3] = a3;
    }
}

// ---------------- fused mean-pool (binary search on sorted batch) + MLP head ----------------
__global__ __launch_bounds__(256) void pool_head_kernel(
    const float* __restrict__ A, const int* __restrict__ batch,
    const float* __restrict__ W3, const float* __restrict__ b3,
    const float* __restrict__ W4, const float* __restrict__ b4,
    float* __restrict__ out) {
    __shared__ int   sb[2];
    __shared__ float sd[4][64];
    __shared__ float gv[64];
    int gidx = blockIdx.x;
    int t = threadIdx.x;
    if (t < 2) {
        int target = gidx + t;
        int lo = 0, hi = N_NODES;
        while (lo < hi) {
            int mid = (lo + hi) >> 1;
            if (batch[mid] < target) lo = mid + 1; else hi = mid;
        }
        sb[t] = lo;
    }
    __syncthreads();
    int start = sb[0], end = sb[1];
    int col = t & 63, rg = t >> 6;
    float sum = 0.f;
    for (int r = start + rg; r < end; r += 4) sum += A[(size_t)r * HIDDEN + col];
    sd[rg][col] = sum;
    __syncthreads();
    if (t < 64) {
        float tot = sd[0][col] + sd[1][col] + sd[2][col] + sd[3][col];
        float cnt = (float)(end - start);
        gv[col] = tot / fmaxf(cnt, 1.0f);
    }
    __syncthreads();
    if (t < 64) {
        float acc = b3[t];
        #pragma unroll
        for (int k = 0; k < 64; ++k) acc = fmaf(gv[k], W3[k * 64 + t], acc);
        float p = fmaxf(acc, 0.f) * W4[t];
        #pragma unroll
        for (int o = 32; o > 0; o >>= 1) p += __shfl_down(p, o, 64);
        if (t == 0) out[gidx] = p + b4[0];
    }
}

extern "C" void kernel_launch(void* const* d_in, const int* in_sizes, int n_in,
                              void* d_out, int out_size, void* d_ws, size_t ws_size,
                              hipStream_t stream) {
    const int*   labels = (const int*)d_in[0];
    const int*   ei     = (const int*)d_in[1];
    const int*   src    = ei;
    const int*   dst    = ei + N_EDGES;
    const float* ew     = (const float*)d_in[2];
    const int*   batch  = (const int*)d_in[3];
    const float* emb    = (const float*)d_in[4];
    const float* W1 = (const float*)d_in[5],  *b1 = (const float*)d_in[6];
    const float* W2 = (const float*)d_in[7],  *b2 = (const float*)d_in[8];
    const float* W3 = (const float*)d_in[9],  *b3 = (const float*)d_in[10];
    const float* W4 = (const float*)d_in[11], *b4 = (const float*)d_in[12];
    float* out = (float*)d_out;

    // workspace carve
    float* ws   = (float*)d_ws;
    float* bufH = ws;                                       // N*64 fp32 (agg2 out / gemm2 in)
    float* bufA = bufH + (size_t)N_NODES * HIDDEN;          // N*64 fp32 region: barr -> A1h(fp16) -> A2(fp32)
    int2*  csr  = (int2*)(bufA + (size_t)N_NODES * HIDDEN); // E int2
    int*   bcnt   = (int*)(csr + N_EDGES);                  // NBKT
    int*   boff   = bcnt + NBKT;                            // NBKT+1
    int*   bktCur = boff + NBKT + 1;                        // NBKT
    int*   off    = bktCur + NBKT;                          // N+1
    float* dinv   = (float*)(off + N_NODES + 1);            // N
    __half* EW1h  = (__half*)(dinv + N_NODES);              // 1000*64 fp16
    int2*  barr   = (int2*)bufA;                            // aliases bufA (dead after finalize)
    __half* A1h   = (__half*)bufA;                          // fp16 activation, after finalize
    float* A2     = bufA;                                   // fp32 conv2 out (A1h dead after agg2)

    const int NT = 256;
    const int blkW = (N_NODES * 64 + NT - 1) / NT;          // wave per node
    const int blkG = (N_NODES + 63) / 64;

    // ---- CSR build ----
    zero_int_kernel<<<(NBKT + NT - 1) / NT, NT, 0, stream>>>(bcnt, NBKT);
    hist_kernel<<<NBLK_E, NT, 0, stream>>>(dst, bcnt, N_EDGES);
    scan_buckets_kernel<<<1, 1024, 0, stream>>>(bcnt, boff, bktCur);
    bucket_scatter_kernel<<<NBLK_E, NT, 0, stream>>>(src, dst, ew, bktCur, barr, N_EDGES);
    finalize_kernel<<<NBKT, NT, 0, stream>>>(barr, boff, labels, csr, off, dinv);

    // ---- conv1: EW1 = emb@W1 (fp16), direct agg -> A1h ----
    ew1_kernel<<<(NUM_LABELS + 63) / 64, NT, 0, stream>>>(emb, W1, EW1h);
    agg1_kernel<<<blkW, NT, 0, stream>>>(EW1h, labels, csr, off, dinv, b1, A1h, N_NODES);

    // ---- conv2: aggregate A1h -> bufH, GEMM -> A2 ----
    agg2_kernel<<<blkW, NT, 0, stream>>>(A1h, csr, off, dinv, bufH, N_NODES);
    gemm2_kernel<<<blkG, NT, 0, stream>>>(bufH, W2, b2, A2, N_NODES);

    // ---- fused mean-pool + head ----
    pool_head_kernel<<<NUM_GRAPHS, NT, 0, stream>>>(A2, batch, W3, b3, W4, b4, out);
}

// Round 10
// 464.221 us; speedup vs baseline: 2.4874x; 1.1762x over previous
//
#include <hip/hip_runtime.h>
#include <hip/hip_fp16.h>

#define N_NODES    100000
#define N_EDGES    3200000
#define HIDDEN     64
#define NUM_GRAPHS 128
#define NUM_LABELS 1000

#define BKT_SHIFT  8
#define NPB        256                              // nodes per bucket
#define NBKT       ((N_NODES + NPB - 1) / NPB)      // 391
#define CHUNK      8192
#define NBLK_E     ((N_EDGES + CHUNK - 1) / CHUNK)  // 391
#define ENTCAP     8960                             // LDS staging capacity (71.7 KB)

// ---------------- zero int fill ----------------
__global__ void zero_int_kernel(int* __restrict__ p, int n) {
    int i = blockIdx.x * blockDim.x + threadIdx.x;
    if (i < n) p[i] = 0;
}

// ---------------- K1: bucket histogram ----------------
__global__ __launch_bounds__(256) void hist_kernel(const int* __restrict__ dst,
                                                   int* __restrict__ bcnt, int E) {
    __shared__ int h[NBKT];
    int t = threadIdx.x;
    for (int b = t; b < NBKT; b += 256) h[b] = 0;
    __syncthreads();
    int base = blockIdx.x * CHUNK;
    int end  = min(base + CHUNK, E);
    for (int i = base + t; i < end; i += 256)
        atomicAdd(&h[dst[i] >> BKT_SHIFT], 1);
    __syncthreads();
    for (int b = t; b < NBKT; b += 256) {
        int c = h[b];
        if (c) atomicAdd(&bcnt[b], c);
    }
}

// ---------------- K2: scan bucket counts -> offsets + cursors ----------------
__global__ __launch_bounds__(512) void scan_buckets_kernel(const int* __restrict__ bcnt,
                                                           int* __restrict__ boff,
                                                           int* __restrict__ bktCur) {
    __shared__ int a[512], b[512];
    int t = threadIdx.x;
    int v = (t < NBKT) ? bcnt[t] : 0;
    a[t] = v; __syncthreads();
    int* pa = a; int* pb = b;
    #pragma unroll
    for (int d = 1; d < 512; d <<= 1) {
        int x = pa[t];
        if (t >= d) x += pa[t - d];
        pb[t] = x; __syncthreads();
        int* tmp = pa; pa = pb; pb = tmp;
    }
    int ex = (t == 0) ? 0 : pa[t - 1];
    if (t < NBKT) { boff[t] = ex; bktCur[t] = ex; }
    if (t == NBKT - 1) boff[NBKT] = pa[t];
}

// ---------------- K3: scatter edges into bucket-contiguous buffer ----------------
// barr entry: x = src | (dstoff << 20), y = bits(ew)
__global__ __launch_bounds__(256) void bucket_scatter_kernel(
    const int* __restrict__ src, const int* __restrict__ dst,
    const float* __restrict__ ew, int* __restrict__ bktCur,
    int2* __restrict__ barr, int E) {
    __shared__ int h[NBKT];
    __shared__ int wbase[NBKT];
    int t = threadIdx.x;
    for (int b = t; b < NBKT; b += 256) h[b] = 0;
    __syncthreads();
    int base = blockIdx.x * CHUNK;
    int end  = min(base + CHUNK, E);
    for (int i = base + t; i < end; i += 256)
        atomicAdd(&h[dst[i] >> BKT_SHIFT], 1);
    __syncthreads();
    for (int b = t; b < NBKT; b += 256) {
        int c = h[b];
        wbase[b] = c ? atomicAdd(&bktCur[b], c) : 0;
    }
    __syncthreads();
    for (int b = t; b < NBKT; b += 256) h[b] = 0;
    __syncthreads();
    for (int i = base + t; i < end; i += 256) {
        int d = dst[i];
        int bk = d >> BKT_SHIFT;
        int p = atomicAdd(&h[bk], 1);
        barr[wbase[bk] + p] = make_int2(src[i] | ((d & (NPB - 1)) << 20),
                                        __float_as_int(ew[i]));
    }
}

// ---------------- K4: merged per-bucket finalize -> off + dinv + CSR ----------------
// csr entry: x = src | (labels[src] << 17), y = bits(ew * dinv[dst])
__global__ __launch_bounds__(256) void finalize_kernel(
    const int2* __restrict__ barr, const int* __restrict__ boff,
    const int* __restrict__ labels,
    int2* __restrict__ csr, int* __restrict__ off, float* __restrict__ dinv) {
    __shared__ int2  ent[ENTCAP];
    __shared__ int   hcnt[NPB];
    __shared__ float wsum[NPB];
    __shared__ float ldv[NPB];
    __shared__ int   ha[NPB], hcur[NPB];
    int b = blockIdx.x;
    int t = threadIdx.x;
    int s = boff[b], e = boff[b + 1];
    int m = e - s;
    int node0 = b << BKT_SHIFT;
    int nn = min(NPB, N_NODES - node0);
    if (t < NPB) { hcnt[t] = 0; wsum[t] = 0.f; }
    // NPB=256 == blockDim, single stride
    __syncthreads();
    bool staged = (m <= ENTCAP);
    for (int i = t; i < m; i += 256) {
        int2 v = barr[s + i];
        if (staged) ent[i] = v;
        int doff = (v.x >> 20) & (NPB - 1);
        atomicAdd(&hcnt[doff], 1);
        atomicAdd(&wsum[doff], __int_as_float(v.y));
    }
    __syncthreads();
    ha[t] = hcnt[t];
    __syncthreads();
    #pragma unroll
    for (int d = 1; d < NPB; d <<= 1) {
        int x = ha[t];
        if (t >= d) x += ha[t - d];
        __syncthreads();
        ha[t] = x;
        __syncthreads();
    }
    {
        int ex = (t == 0) ? 0 : ha[t - 1];
        hcur[t] = s + ex;
        float dv = rsqrtf(wsum[t] + 1.0f);
        ldv[t] = dv;
        if (t < nn) {
            off[node0 + t]  = s + ex;
            dinv[node0 + t] = dv;
        }
    }
    if (b == NBKT - 1 && t == 0) off[N_NODES] = e;
    __syncthreads();
    for (int i = t; i < m; i += 256) {
        int2 v = staged ? ent[i] : barr[s + i];
        int doff = (v.x >> 20) & (NPB - 1);
        int sv   = v.x & 0xFFFFF;                  // src (17 bits used)
        float wf = __int_as_float(v.y) * ldv[doff];    // dinv[dst] folded
        int lab  = labels[sv];
        int p = atomicAdd(&hcur[doff], 1);
        csr[p] = make_int2(sv | (lab << 17), __float_as_int(wf));
    }
}

// ---------------- EW1 = emb @ W1 (1000x64), fp16 out ----------------
__global__ __launch_bounds__(256) void ew1_kernel(
    const float* __restrict__ emb, const float* __restrict__ W,
    __half* __restrict__ OUTH) {
    __shared__ float Ws[64 * 64];
    __shared__ float Xs[64 * 65];
    int t = threadIdx.x;
    #pragma unroll
    for (int s = 0; s < 16; ++s) Ws[s * 256 + t] = W[s * 256 + t];
    int r0   = blockIdx.x * 64;
    int lrow = t >> 2;
    int c0   = (t & 3) * 16;
    int grow = r0 + lrow;
    const float* srcrow = (grow < NUM_LABELS) ? (emb + (size_t)grow * HIDDEN) : emb;
    #pragma unroll
    for (int c = 0; c < 16; c += 4) {
        float4 v = *(const float4*)(srcrow + c0 + c);
        Xs[lrow * 65 + c0 + c + 0] = v.x;
        Xs[lrow * 65 + c0 + c + 1] = v.y;
        Xs[lrow * 65 + c0 + c + 2] = v.z;
        Xs[lrow * 65 + c0 + c + 3] = v.w;
    }
    __syncthreads();
    int row = t & 63;
    int j0  = (t >> 6) * 16;
    float4 a0 = make_float4(0,0,0,0), a1 = a0, a2 = a0, a3 = a0;
    #pragma unroll
    for (int k = 0; k < 64; ++k) {
        float xv = Xs[row * 65 + k];
        const float4* wr = (const float4*)(Ws + k * 64 + j0);
        float4 w0 = wr[0], w1 = wr[1], w2 = wr[2], w3 = wr[3];
        a0.x = fmaf(xv, w0.x, a0.x); a0.y = fmaf(xv, w0.y, a0.y);
        a0.z = fmaf(xv, w0.z, a0.z); a0.w = fmaf(xv, w0.w, a0.w);
        a1.x = fmaf(xv, w1.x, a1.x); a1.y = fmaf(xv, w1.y, a1.y);
        a1.z = fmaf(xv, w1.z, a1.z); a1.w = fmaf(xv, w1.w, a1.w);
        a2.x = fmaf(xv, w2.x, a2.x); a2.y = fmaf(xv, w2.y, a2.y);
        a2.z = fmaf(xv, w2.z, a2.z); a2.w = fmaf(xv, w2.w, a2.w);
        a3.x = fmaf(xv, w3.x, a3.x); a3.y = fmaf(xv, w3.y, a3.y);
        a3.z = fmaf(xv, w3.z, a3.z); a3.w = fmaf(xv, w3.w, a3.w);
    }
    int gr = r0 + row;
    if (gr < NUM_LABELS) {
        union { __half2 h2[8]; uint4 u4[2]; } pk;
        pk.h2[0] = __floats2half2_rn(a0.x, a0.y);
        pk.h2[1] = __floats2half2_rn(a0.z, a0.w);
        pk.h2[2] = __floats2half2_rn(a1.x, a1.y);
        pk.h2[3] = __floats2half2_rn(a1.z, a1.w);
        pk.h2[4] = __floats2half2_rn(a2.x, a2.y);
        pk.h2[5] = __floats2half2_rn(a2.z, a2.w);
        pk.h2[6] = __floats2half2_rn(a3.x, a3.y);
        pk.h2[7] = __floats2half2_rn(a3.z, a3.w);
        uint4* o = (uint4*)(OUTH + (size_t)gr * HIDDEN + j0);
        o[0] = pk.u4[0]; o[1] = pk.u4[1];
    }
}

// ---------------- conv1: agg over EW1[label] -> A1 = relu(acc + di2*self + b1), fp16 out ----------------
__global__ __launch_bounds__(256) void agg1_kernel(
    const __half* __restrict__ EW1h, const int* __restrict__ labels,
    const int2* __restrict__ csr, const int* __restrict__ off,
    const float* __restrict__ dinv, const float* __restrict__ bias,
    __half* __restrict__ A1h, int n) {
    int wid  = (blockIdx.x * blockDim.x + threadIdx.x) >> 6;
    if (wid >= n) return;
    int lane = threadIdx.x & 63;
    int q = lane & 15, g = lane >> 4;
    int i   = off[wid] + g;
    int end = off[wid + 1];
    float4 acc = make_float4(0.f, 0.f, 0.f, 0.f);
    int2 e0 = (i     < end) ? csr[i]     : make_int2(0, 0);
    int2 e1 = (i + 4 < end) ? csr[i + 4] : make_int2(0, 0);
    uint2  r0 = *(const uint2*)(EW1h + (size_t)((unsigned)e0.x >> 17) * HIDDEN + q * 4);
    float  w0 = __int_as_float(e0.y) * dinv[e0.x & 0x1FFFF];
    while (i < end) {
        int2 e2 = (i + 8 < end) ? csr[i + 8] : make_int2(0, 0);
        uint2  r1 = *(const uint2*)(EW1h + (size_t)((unsigned)e1.x >> 17) * HIDDEN + q * 4);
        float  w1 = __int_as_float(e1.y) * dinv[e1.x & 0x1FFFF];
        const __half2* hp = (const __half2*)&r0;
        float2 f01 = __half22float2(hp[0]);
        float2 f23 = __half22float2(hp[1]);
        acc.x = fmaf(f01.x, w0, acc.x);
        acc.y = fmaf(f01.y, w0, acc.y);
        acc.z = fmaf(f23.x, w0, acc.z);
        acc.w = fmaf(f23.y, w0, acc.w);
        w0 = w1; r0 = r1; e1 = e2;
        i += 4;
    }
    acc.x += __shfl_xor(acc.x, 16, 64); acc.y += __shfl_xor(acc.y, 16, 64);
    acc.z += __shfl_xor(acc.z, 16, 64); acc.w += __shfl_xor(acc.w, 16, 64);
    acc.x += __shfl_xor(acc.x, 32, 64); acc.y += __shfl_xor(acc.y, 32, 64);
    acc.z += __shfl_xor(acc.z, 32, 64); acc.w += __shfl_xor(acc.w, 32, 64);
    if (g == 0) {
        float di  = dinv[wid];
        float di2 = di * di;
        int labw = labels[wid];
        uint2 xu = *(const uint2*)(EW1h + (size_t)labw * HIDDEN + q * 4);
        const __half2* xp = (const __half2*)&xu;
        float2 x01 = __half22float2(xp[0]);
        float2 x23 = __half22float2(xp[1]);
        float4 bv = *(const float4*)(bias + q * 4);
        float4 v;
        v.x = fmaxf(fmaf(x01.x, di2, acc.x) + bv.x, 0.f);
        v.y = fmaxf(fmaf(x01.y, di2, acc.y) + bv.y, 0.f);
        v.z = fmaxf(fmaf(x23.x, di2, acc.z) + bv.z, 0.f);
        v.w = fmaxf(fmaf(x23.y, di2, acc.w) + bv.w, 0.f);
        union { __half2 h2[2]; uint2 u2; } pk;
        pk.h2[0] = __floats2half2_rn(v.x, v.y);
        pk.h2[1] = __floats2half2_rn(v.z, v.w);
        *(uint2*)(A1h + (size_t)wid * HIDDEN + q * 4) = pk.u2;
    }
}

// ---------------- conv2 pull aggregation (fp16 activation gather) -> fp32 out ----------------
__global__ __launch_bounds__(256) void agg2_kernel(
    const __half* __restrict__ Xh,
    const int2* __restrict__ csr, const int* __restrict__ off,
    const float* __restrict__ dinv, float* __restrict__ OUT, int n) {
    int wid  = (blockIdx.x * blockDim.x + threadIdx.x) >> 6;
    if (wid >= n) return;
    int lane = threadIdx.x & 63;
    int q = lane & 15, g = lane >> 4;
    int i   = off[wid] + g;
    int end = off[wid + 1];
    float4 acc = make_float4(0.f, 0.f, 0.f, 0.f);
    int2 e0 = (i     < end) ? csr[i]     : make_int2(0, 0);
    int2 e1 = (i + 4 < end) ? csr[i + 4] : make_int2(0, 0);
    uint2  r0 = *(const uint2*)(Xh + (size_t)(e0.x & 0x1FFFF) * HIDDEN + q * 4);
    float  w0 = __int_as_float(e0.y) * dinv[e0.x & 0x1FFFF];
    while (i < end) {
        int2 e2 = (i + 8 < end) ? csr[i + 8] : make_int2(0, 0);
        uint2  r1 = *(const uint2*)(Xh + (size_t)(e1.x & 0x1FFFF) * HIDDEN + q * 4);
        float  w1 = __int_as_float(e1.y) * dinv[e1.x & 0x1FFFF];
        const __half2* hp = (const __half2*)&r0;
        float2 f01 = __half22float2(hp[0]);
        float2 f23 = __half22float2(hp[1]);
        acc.x = fmaf(f01.x, w0, acc.x);
        acc.y = fmaf(f01.y, w0, acc.y);
        acc.z = fmaf(f23.x, w0, acc.z);
        acc.w = fmaf(f23.y, w0, acc.w);
        w0 = w1; r0 = r1; e1 = e2;
        i += 4;
    }
    acc.x += __shfl_xor(acc.x, 16, 64); acc.y += __shfl_xor(acc.y, 16, 64);
    acc.z += __shfl_xor(acc.z, 16, 64); acc.w += __shfl_xor(acc.w, 16, 64);
    acc.x += __shfl_xor(acc.x, 32, 64); acc.y += __shfl_xor(acc.y, 32, 64);
    acc.z += __shfl_xor(acc.z, 32, 64); acc.w += __shfl_xor(acc.w, 32, 64);
    if (g == 0) {
        float di  = dinv[wid];
        float di2 = di * di;
        uint2 xu = *(const uint2*)(Xh + (size_t)wid * HIDDEN + q * 4);
        const __half2* xp = (const __half2*)&xu;
        float2 x01 = __half22float2(xp[0]);
        float2 x23 = __half22float2(xp[1]);
        float4 v;
        v.x = fmaf(x01.x, di2, acc.x);
        v.y = fmaf(x01.y, di2, acc.y);
        v.z = fmaf(x23.x, di2, acc.z);
        v.w = fmaf(x23.y, di2, acc.w);
        *(float4*)(OUT + (size_t)wid * HIDDEN + q * 4) = v;
    }
}

// ---------------- GEMM + bias + relu -> fp32 out ----------------
__global__ __launch_bounds__(256) void gemm2_kernel(
    const float* __restrict__ X, const float* __restrict__ W,
    const float* __restrict__ bias, float* __restrict__ OUT, int n) {
    __shared__ float Ws[64 * 64];
    __shared__ float Xs[64 * 65];
    int t = threadIdx.x;
    #pragma unroll
    for (int s = 0; s < 16; ++s) Ws[s * 256 + t] = W[s * 256 + t];
    int r0   = blockIdx.x * 64;
    int lrow = t >> 2;
    int c0   = (t & 3) * 16;
    int grow = r0 + lrow;
    const float* srcrow = (grow < n) ? (X + (size_t)grow * HIDDEN) : X;
    #pragma unroll
    for (int c = 0; c < 16; c += 4) {
        float4 v = *(const float4*)(srcrow + c0 + c);
        Xs[lrow * 65 + c0 + c + 0] = v.x;
        Xs[lrow * 65 + c0 + c + 1] = v.y;
        Xs[lrow * 65 + c0 + c + 2] = v.z;
        Xs[lrow * 65 + c0 + c + 3] = v.w;
    }
    __syncthreads();
    int row = t & 63;
    int j0  = (t >> 6) * 16;
    float4 a0 = *(const float4*)(bias + j0 + 0);
    float4 a1 = *(const float4*)(bias + j0 + 4);
    float4 a2 = *(const float4*)(bias + j0 + 8);
    float4 a3 = *(const float4*)(bias + j0 + 12);
    #pragma unroll
    for (int k = 0; k < 64; ++k) {
        float xv = Xs[row * 65 + k];
        const float4* wr = (const float4*)(Ws + k * 64 + j0);
        float4 w0 = wr[0], w1 = wr[1], w2 = wr[2], w3 = wr[3];
        a0.x = fmaf(xv, w0.x, a0.x); a0.y = fmaf(xv, w0.y, a0.y);
        a0.z = fmaf(xv, w0.z, a0.z); a0.w = fmaf(xv, w0.w, a0.w);
        a1.x = fmaf(xv, w1.x, a1.x); a1.y = fmaf(xv, w1.y, a1.y);
        a1.z = fmaf(xv, w1.z, a1.z); a1.w = fmaf(xv, w1.w, a1.w);
        a2.x = fmaf(xv, w2.x, a2.x); a2.y = fmaf(xv, w2.y, a2.y);
        a2.z = fmaf(xv, w2.z, a2.z); a2.w = fmaf(xv, w2.w, a2.w);
        a3.x = fmaf(xv, w3.x, a3.x); a3.y = fmaf(xv, w3.y, a3.y);
        a3.z = fmaf(xv, w3.z, a3.z); a3.w = fmaf(xv, w3.w, a3.w);
    }
    int gr = r0 + row;
    if (gr < n) {
        float4* o = (float4*)(OUT + (size_t)gr * HIDDEN + j0);
        a0.x = fmaxf(a0.x, 0.f); a0.y = fmaxf(a0.y, 0.f); a0.z = fmaxf(a0.z, 0.f); a0.w = fmaxf(a0.w, 0.f);
        a1.x = fmaxf(a1.x, 0.f); a1.y = fmaxf(a1.y, 0.f); a1.z = fmaxf(a1.z, 0.f); a1.w = fmaxf(a1.w, 0.f);
        a2.x = fmaxf(a2.x, 0.f); a2.y = fmaxf(a2.y, 0.f); a2.z = fmaxf(a2.z, 0.f); a2.w = fmaxf(a2.w, 0.f);
        a3.x = fmaxf(a3.x, 0.f); a3.y = fmaxf(a3.y, 0.f); a3.z = fmaxf(a3.z, 0.f); a3.w = fmaxf(a3.w, 0.f);
        o[0] = a0; o[1] = a1; o[2] = a2; o[3] = a3;
    }
}

// ---------------- fused mean-pool (binary search on sorted batch) + MLP head ----------------
__global__ __launch_bounds__(256) void pool_head_kernel(
    const float* __restrict__ A, const int* __restrict__ batch,
    const float* __restrict__ W3, const float* __restrict__ b3,
    const float* __restrict__ W4, const float* __restrict__ b4,
    float* __restrict__ out) {
    __shared__ int   sb[2];
    __shared__ float sd[4][64];
    __shared__ float gv[64];
    int gidx = blockIdx.x;
    int t = threadIdx.x;
    if (t < 2) {
        int target = gidx + t;
        int lo = 0, hi = N_NODES;
        while (lo < hi) {
            int mid = (lo + hi) >> 1;
            if (batch[mid] < target) lo = mid + 1; else hi = mid;
        }
        sb[t] = lo;
    }
    __syncthreads();
    int start = sb[0], end = sb[1];
    int col = t & 63, rg = t >> 6;
    float sum = 0.f;
    for (int r = start + rg; r < end; r += 4) sum += A[(size_t)r * HIDDEN + col];
    sd[rg][col] = sum;
    __syncthreads();
    if (t < 64) {
        float tot = sd[0][col] + sd[1][col] + sd[2][col] + sd[3][col];
        float cnt = (float)(end - start);
        gv[col] = tot / fmaxf(cnt, 1.0f);
    }
    __syncthreads();
    if (t < 64) {
        float acc = b3[t];
        #pragma unroll
        for (int k = 0; k < 64; ++k) acc = fmaf(gv[k], W3[k * 64 + t], acc);
        float p = fmaxf(acc, 0.f) * W4[t];
        #pragma unroll
        for (int o = 32; o > 0; o >>= 1) p += __shfl_down(p, o, 64);
        if (t == 0) out[gidx] = p + b4[0];
    }
}

extern "C" void kernel_launch(void* const* d_in, const int* in_sizes, int n_in,
                              void* d_out, int out_size, void* d_ws, size_t ws_size,
                              hipStream_t stream) {
    const int*   labels = (const int*)d_in[0];
    const int*   ei     = (const int*)d_in[1];
    const int*   src    = ei;
    const int*   dst    = ei + N_EDGES;
    const float* ew     = (const float*)d_in[2];
    const int*   batch  = (const int*)d_in[3];
    const float* emb    = (const float*)d_in[4];
    const float* W1 = (const float*)d_in[5],  *b1 = (const float*)d_in[6];
    const float* W2 = (const float*)d_in[7],  *b2 = (const float*)d_in[8];
    const float* W3 = (const float*)d_in[9],  *b3 = (const float*)d_in[10];
    const float* W4 = (const float*)d_in[11], *b4 = (const float*)d_in[12];
    float* out = (float*)d_out;

    // workspace carve
    float* ws   = (float*)d_ws;
    float* bufH = ws;                                       // N*64 fp32 (agg2 out / gemm2 in)
    float* bufA = bufH + (size_t)N_NODES * HIDDEN;          // N*64 fp32 region: barr -> A1h(fp16) -> A2(fp32)
    int2*  csr  = (int2*)(bufA + (size_t)N_NODES * HIDDEN); // E int2
    int*   bcnt   = (int*)(csr + N_EDGES);                  // NBKT
    int*   boff   = bcnt + NBKT;                            // NBKT+1
    int*   bktCur = boff + NBKT + 1;                        // NBKT
    int*   off    = bktCur + NBKT;                          // N+1
    float* dinv   = (float*)(off + N_NODES + 1);            // N
    __half* EW1h  = (__half*)(dinv + N_NODES);              // 1000*64 fp16
    int2*  barr   = (int2*)bufA;                            // aliases bufA (dead after finalize)
    __half* A1h   = (__half*)bufA;                          // fp16 activation, after finalize
    float* A2     = bufA;                                   // fp32 conv2 out (A1h dead after agg2)

    const int NT = 256;
    const int blkW = (N_NODES * 64 + NT - 1) / NT;          // wave per node
    const int blkG = (N_NODES + 63) / 64;

    // ---- CSR build ----
    zero_int_kernel<<<(NBKT + NT - 1) / NT, NT, 0, stream>>>(bcnt, NBKT);
    hist_kernel<<<NBLK_E, NT, 0, stream>>>(dst, bcnt, N_EDGES);
    scan_buckets_kernel<<<1, 512, 0, stream>>>(bcnt, boff, bktCur);
    bucket_scatter_kernel<<<NBLK_E, NT, 0, stream>>>(src, dst, ew, bktCur, barr, N_EDGES);
    finalize_kernel<<<NBKT, NT, 0, stream>>>(barr, boff, labels, csr, off, dinv);

    // ---- conv1: EW1 = emb@W1 (fp16), direct agg -> A1h ----
    ew1_kernel<<<(NUM_LABELS + 63) / 64, NT, 0, stream>>>(emb, W1, EW1h);
    agg1_kernel<<<blkW, NT, 0, stream>>>(EW1h, labels, csr, off, dinv, b1, A1h, N_NODES);

    // ---- conv2: aggregate A1h -> bufH, GEMM -> A2 ----
    agg2_kernel<<<blkW, NT, 0, stream>>>(A1h, csr, off, dinv, bufH, N_NODES);
    gemm2_kernel<<<blkG, NT, 0, stream>>>(bufH, W2, b2, A2, N_NODES);

    // ---- fused mean-pool + head ----
    pool_head_kernel<<<NUM_GRAPHS, NT, 0, stream>>>(A2, batch, W3, b3, W4, b4, out);
}